// Round 10
// baseline (287.134 us; speedup 1.0000x reference)
//
#include <hip/hip_runtime.h>
#include <hip/hip_bf16.h>

#define NF 128
#define TILE_B 8192
#define CSR_CAP 15360

typedef __attribute__((ext_vector_type(8))) short bf8;
typedef __attribute__((ext_vector_type(4))) float f4;
typedef unsigned short u16x8 __attribute__((ext_vector_type(8)));

static __device__ __forceinline__ unsigned short f2bf(float f) {
  unsigned u = __builtin_bit_cast(unsigned, f);
  u = u + 0x7FFF + ((u >> 16) & 1);            // RNE
  return (unsigned short)(u >> 16);
}

static __device__ __forceinline__ uint4 pkmax4(uint4 a, uint4 b) {
  u16x8 x = __builtin_bit_cast(u16x8, a);
  u16x8 y = __builtin_bit_cast(u16x8, b);
  u16x8 m = __builtin_elementwise_max(x, y);   // v_pk_max_u16: valid for relu'd bf16 (>=0)
  return __builtin_bit_cast(uint4, m);
}

// ---------------- prep: fp32->bf16 convert (all blocks) + dst bucket hist + W pack ----------------

__global__ __launch_bounds__(256) void k_prep(
    const float* __restrict__ x, unsigned short* __restrict__ Xb, long long nelX,
    const int* __restrict__ dst, int* __restrict__ bcnt, int E, int gTile,
    const float* W0, const float* W1, const float* W2,
    const float* W3, const float* W4, const float* W5,
    unsigned short* __restrict__ Wpack) {
  __shared__ int h[256];
  int b = blockIdx.x, tid = threadIdx.x;

  long long i = ((long long)b * 256 + tid) * 8;
  if (i + 8 <= nelX) {
    float4 a = *(const float4*)(x + i);
    float4 c = *(const float4*)(x + i + 4);
    uint4 o;
    o.x = f2bf(a.x) | ((unsigned)f2bf(a.y) << 16);
    o.y = f2bf(a.z) | ((unsigned)f2bf(a.w) << 16);
    o.z = f2bf(c.x) | ((unsigned)f2bf(c.y) << 16);
    o.w = f2bf(c.z) | ((unsigned)f2bf(c.w) << 16);
    *(uint4*)(Xb + i) = o;
  }

  if (b < gTile) {                       // bucket histogram tile
    h[tid] = 0;
    __syncthreads();
    int t0 = b * TILE_B;
    int tend = min(E, t0 + TILE_B);
    for (int k = t0 + tid; k < tend; k += 256) atomicAdd(&h[dst[k] >> 8], 1);
    __syncthreads();
    if (h[tid] > 0) atomicAdd(&bcnt[tid], h[tid]);
  } else if (b < gTile + 48) {           // pack 6 matrices: 48*256 = 6*2048 units
    int gid = (b - gTile) * 256 + tid;
    int m = gid >> 11;
    int u = gid & 2047;
    const float* W = (m == 0) ? W0 : (m == 1) ? W1 : (m == 2) ? W2
                   : (m == 3) ? W3 : (m == 4) ? W4 : W5;
    int l = u & 63, c = u >> 6;
    int kk = c & 3, t = c >> 2;
    int kb = kk * 32 + ((l >> 4) << 3);
    int n = t * 16 + (l & 15);
    unsigned short* o = Wpack + (size_t)m * 2048 * 8 + (size_t)u * 8;
    #pragma unroll
    for (int j = 0; j < 8; ++j) o[j] = f2bf(W[(size_t)(kb + j) * NF + n]);
  }
}

// ---------------- pool GEMM body: Y = relu(A@W + b), 64 rows/block, W in LDS (32 KB) ----------

static __device__ __forceinline__ void pool_body(
    char* smem, int tile,
    const unsigned short* __restrict__ A, const unsigned short* __restrict__ P,
    const float* __restrict__ bias, unsigned short* __restrict__ Yout, int M) {
  int tid = threadIdx.x, w = tid >> 6, lane = tid & 63;
  int r0 = lane & 15, g = lane >> 4;
  {
    uint4* S = (uint4*)smem;
    const uint4* Pv = (const uint4*)P;
    for (int t = tid; t < 2048; t += 256) S[t] = Pv[t];
  }
  float bb[8];
  #pragma unroll
  for (int t = 0; t < 8; ++t) bb[t] = bias[t * 16 + r0];
  __syncthreads();

  int base = tile * 64;
  int arow = min(base + w * 16 + r0, M - 1);
  f4 acc[8];
  #pragma unroll
  for (int t = 0; t < 8; ++t) acc[t] = (f4){0.f, 0.f, 0.f, 0.f};
  const bf8* Ar = (const bf8*)(A + (size_t)arow * NF);
  const bf8* Wl = (const bf8*)smem;
  #pragma unroll
  for (int kk = 0; kk < 4; ++kk) {
    bf8 a = Ar[kk * 4 + g];
    #pragma unroll
    for (int t = 0; t < 8; ++t)
      acc[t] = __builtin_amdgcn_mfma_f32_16x16x32_bf16(a, Wl[(t * 4 + kk) * 64 + lane], acc[t], 0, 0, 0);
  }
  __syncthreads();
  unsigned short* So = (unsigned short*)smem;   // 64x128 bf16 = 16 KB
  #pragma unroll
  for (int i = 0; i < 4; ++i)
    #pragma unroll
    for (int t = 0; t < 8; ++t)
      So[(w * 16 + g * 4 + i) * NF + t * 16 + r0] = f2bf(fmaxf(acc[t][i] + bb[t], 0.f));
  __syncthreads();
  int maxc = min(64, M - base) * 16;
  uint4* Og = (uint4*)(Yout + (size_t)base * NF);
  const uint4* Sv = (const uint4*)smem;
  for (int c = tid; c < 1024; c += 256)
    if (c < maxc) Og[c] = Sv[c];
}

// ---------------- K3: binB (tile counting-sort by 256-dst bucket) || pool-1 part A ----------

__global__ __launch_bounds__(256) void k_binB_pool(
    const int* __restrict__ src, const int* __restrict__ dst,
    const int* __restrict__ bcnt, int* __restrict__ gcur,
    unsigned* __restrict__ tmp, int E, int gTile,
    const unsigned short* __restrict__ A, const unsigned short* __restrict__ P,
    const float* __restrict__ bias, unsigned short* __restrict__ Yout, int M) {
  __shared__ __align__(16) char smem[37888];   // binB: 5KB ctl + 32KB sorted; pool: 32KB
  int b = blockIdx.x;
  if (b >= gTile) { pool_body(smem, b - gTile, A, P, bias, Yout, M); return; }

  int tid = threadIdx.x;
  int* h  = (int*)smem;
  int* hs = h + 256;
  int* gb = hs + 256;
  int* lc = gb + 256;
  int* bo = lc + 256;
  unsigned* sorted = (unsigned*)(bo + 256);

  int t0 = b * TILE_B;
  int tcnt = min(E - t0, TILE_B);

  int bv = bcnt[tid];                    // scan bcnt -> bo (exclusive)
  hs[tid] = bv;
  __syncthreads();
  for (int d = 1; d < 256; d <<= 1) {
    int t = (tid >= d) ? hs[tid - d] : 0;
    __syncthreads();
    hs[tid] += t;
    __syncthreads();
  }
  bo[tid] = hs[tid] - bv;
  h[tid] = 0;
  __syncthreads();

  for (int i = tid; i < tcnt; i += 256) atomicAdd(&h[dst[t0 + i] >> 8], 1);
  __syncthreads();
  int v = h[tid];
  hs[tid] = v;
  __syncthreads();
  for (int d = 1; d < 256; d <<= 1) {
    int t = (tid >= d) ? hs[tid - d] : 0;
    __syncthreads();
    hs[tid] += t;
    __syncthreads();
  }
  lc[tid] = 0;
  gb[tid] = bo[tid] + ((v > 0) ? atomicAdd(&gcur[tid], v) : 0);
  __syncthreads();
  for (int i = tid; i < tcnt; i += 256) {
    int d = dst[t0 + i];
    unsigned s = (unsigned)src[t0 + i];
    int bk = d >> 8;
    int p = (hs[bk] - h[bk]) + atomicAdd(&lc[bk], 1);
    sorted[p] = ((unsigned)bk << 24) | (s << 8) | (unsigned)(d & 255);
  }
  __syncthreads();
  for (int i = tid; i < tcnt; i += 256) {
    unsigned ev = sorted[i];
    int bk = ev >> 24;
    tmp[gb[bk] + (i - (hs[bk] - h[bk]))] = ev & 0xFFFFFFu;
  }
}

// ---------------- K4: binC (per-bucket CSR in LDS, coalesced flush) || pool-1 part B ----------

__global__ __launch_bounds__(256) void k_binC_pool(
    const unsigned* __restrict__ tmp, const int* __restrict__ bcnt,
    int* __restrict__ off, unsigned short* __restrict__ esrc, int N, int E, int NB,
    const unsigned short* __restrict__ A, const unsigned short* __restrict__ P,
    const float* __restrict__ bias, unsigned short* __restrict__ Yout, int M, int tileOff) {
  __shared__ __align__(16) char smem[66560];   // binC: 5KB ctl + 60KB csr; pool: 32KB
  int b = blockIdx.x;
  if (b >= NB) { pool_body(smem, tileOff + b - NB, A, P, bias, Yout, M); return; }

  int tid = threadIdx.x;
  int* s256 = (int*)smem;
  int* bo   = s256 + 256;
  int* lh   = bo + 256;
  int* ls   = lh + 256;
  int* lcur = ls + 256;
  int* csr  = lcur + 256;
  int base = b << 8;

  int bv = bcnt[tid];                    // scan bcnt -> bo (exclusive)
  s256[tid] = bv;
  __syncthreads();
  for (int d = 1; d < 256; d <<= 1) {
    int t = (tid >= d) ? s256[tid - d] : 0;
    __syncthreads();
    s256[tid] += t;
    __syncthreads();
  }
  bo[tid] = s256[tid] - bv;
  lh[tid] = 0;
  __syncthreads();

  int beg = bo[b];
  int cnt = bcnt[b];
  int end = beg + cnt;

  for (int i = beg + tid; i < end; i += 256) atomicAdd(&lh[tmp[i] & 255], 1);
  __syncthreads();
  int v = lh[tid];
  ls[tid] = v;
  __syncthreads();
  for (int d = 1; d < 256; d <<= 1) {
    int t = (tid >= d) ? ls[tid - d] : 0;
    __syncthreads();
    ls[tid] += t;
    __syncthreads();
  }
  if (base + tid < N) off[base + tid] = beg + (ls[tid] - v);
  if (b == 0 && tid == 0) off[N] = E;
  lcur[tid] = 0;
  __syncthreads();

  if (cnt <= CSR_CAP) {
    for (int i = beg + tid; i < end; i += 256) {
      unsigned e = tmp[i];
      int dl = (int)(e & 255);
      int p = (ls[dl] - lh[dl]) + atomicAdd(&lcur[dl], 1);
      csr[p] = (int)(e >> 8);
    }
    __syncthreads();
    for (int i = tid; i < cnt; i += 256) esrc[beg + i] = (unsigned short)csr[i];
  } else {                                // overflow fallback (never for this data)
    for (int i = beg + tid; i < end; i += 256) {
      unsigned e = tmp[i];
      int dl = (int)(e & 255);
      int p = (ls[dl] - lh[dl]) + atomicAdd(&lcur[dl], 1);
      esrc[beg + p] = (unsigned short)(e >> 8);
    }
  }
}

// ---------------- gather-max: one 16-lane GROUP per dst; full 256B row per load ----------------
// 4 dsts per wave. Group's 16 lanes each load 16B of one row -> 1 row/instr; 8-deep unroll
// gives 32 independent loads in flight per wave. Clamped duplicate edges are max-idempotent.

__global__ __launch_bounds__(256) void k_gather_max(
    const unsigned short* __restrict__ Y, const int* __restrict__ off,
    const unsigned short* __restrict__ esrc, unsigned short* __restrict__ AGG, int N) {
  int lane = threadIdx.x & 63;
  int g = lane >> 4, r0 = lane & 15;
  int wave = (blockIdx.x * 256 + threadIdx.x) >> 6;
  int node = wave * 4 + g;
  bool valid = node < N;
  int nc = min(node, N - 1);
  int s = off[nc];
  int cnt = valid ? (off[nc + 1] - s) : 0;

  int chunks = (cnt + 15) >> 4;
  chunks = max(chunks, __shfl_xor(chunks, 16, 64));   // wave-uniform loop bound
  chunks = max(chunks, __shfl_xor(chunks, 32, 64));

  uint4 am = (uint4){0u, 0u, 0u, 0u};                 // relu >= 0 -> 0 == empty fill
  const uint4* Yv = (const uint4*)Y;

  for (int c = 0; c < chunks; ++c) {
    int ei = (cnt > 0) ? min(c * 16 + r0, cnt - 1) : 0;
    int idxv = (int)esrc[s + ei];                     // group-coalesced 16 x u16
    int rem = cnt - c * 16;                           // edges left for this group
    int top = max(rem, 1) - 1;                        // clamp index within chunk
    #pragma unroll
    for (int jj = 0; jj < 16; jj += 8) {
      uint4 v[8];
      #pragma unroll
      for (int j = 0; j < 8; ++j) {
        int u = __shfl(idxv, (g << 4) + min(jj + j, min(top, 15)), 64);
        v[j] = Yv[(size_t)u * 16 + r0];               // full row: 16 lanes x 16B
      }
      if (rem > jj) {
        #pragma unroll
        for (int j = 0; j < 8; ++j) am = pkmax4(am, v[j]);
      }
    }
  }
  if (valid) *((uint4*)(AGG + (size_t)node * NF) + r0) = am;
}

// ---------------- fused: H = l2norm_relu(X@Ws + AGG@Wn + b1); Y2 = relu(H@Wp2 + bp2) --------

__global__ __launch_bounds__(256) void k_dual_pool(
    const unsigned short* __restrict__ Xb, const unsigned short* __restrict__ Ps,
    const unsigned short* __restrict__ AGG, const unsigned short* __restrict__ Pn,
    const float* __restrict__ b1,
    const unsigned short* __restrict__ Pp2, const float* __restrict__ bp2,
    unsigned short* __restrict__ Hb, unsigned short* __restrict__ Yb, int M) {
  __shared__ __align__(16) char smem[65536];
  int tid = threadIdx.x, w = tid >> 6, lane = tid & 63;
  int r0 = lane & 15, g = lane >> 4;
  int base = blockIdx.x * 64;
  int arow = min(base + w * 16 + r0, M - 1);
  int maxrows = min(64, M - base);

  {
    uint4* S = (uint4*)smem;
    const uint4* Pv0 = (const uint4*)Ps;
    const uint4* Pv1 = (const uint4*)Pn;
    for (int t = tid; t < 2048; t += 256) S[t] = Pv0[t];
    for (int t = tid; t < 2048; t += 256) S[2048 + t] = Pv1[t];
  }
  float bb[8], bb2[8];
  #pragma unroll
  for (int t = 0; t < 8; ++t) { bb[t] = b1[t * 16 + r0]; bb2[t] = bp2[t * 16 + r0]; }
  __syncthreads();

  f4 acc[8];
  #pragma unroll
  for (int t = 0; t < 8; ++t) acc[t] = (f4){0.f, 0.f, 0.f, 0.f};
  #pragma unroll
  for (int mat = 0; mat < 2; ++mat) {
    const unsigned short* A = (mat == 0) ? Xb : AGG;
    const bf8* Ar = (const bf8*)(A + (size_t)arow * NF);
    const bf8* Wl = (const bf8*)smem + (size_t)mat * 2048;
    #pragma unroll
    for (int kk = 0; kk < 4; ++kk) {
      bf8 a = Ar[kk * 4 + g];
      #pragma unroll
      for (int t = 0; t < 8; ++t)
        acc[t] = __builtin_amdgcn_mfma_f32_16x16x32_bf16(a, Wl[(t * 4 + kk) * 64 + lane], acc[t], 0, 0, 0);
    }
  }

  float val[8][4];
  #pragma unroll
  for (int t = 0; t < 8; ++t)
    #pragma unroll
    for (int i = 0; i < 4; ++i) val[t][i] = acc[t][i] + bb[t];
  float ss[4] = {0.f, 0.f, 0.f, 0.f};
  #pragma unroll
  for (int i = 0; i < 4; ++i)
    #pragma unroll
    for (int t = 0; t < 8; ++t) ss[i] += val[t][i] * val[t][i];
  #pragma unroll
  for (int d = 1; d < 16; d <<= 1)
    #pragma unroll
    for (int i = 0; i < 4; ++i) ss[i] += __shfl_xor(ss[i], d, 64);
  float inv[4];
  #pragma unroll
  for (int i = 0; i < 4; ++i) inv[i] = 1.f / fmaxf(sqrtf(ss[i]), 1e-12f);

  __syncthreads();                     // W dead
  unsigned short* So = (unsigned short*)smem;   // 64 rows x 136 (padded) bf16
  #pragma unroll
  for (int i = 0; i < 4; ++i)
    #pragma unroll
    for (int t = 0; t < 8; ++t)
      So[(w * 16 + g * 4 + i) * 136 + t * 16 + r0] = f2bf(fmaxf(val[t][i] * inv[i], 0.f));
  __syncthreads();

  {
    uint4* Og = (uint4*)(Hb + (size_t)base * NF);
    for (int c = tid; c < 1024; c += 256) {
      int row = c >> 4, ch = c & 15;
      if (row < maxrows) Og[c] = *(const uint4*)(So + row * 136 + ch * 8);
    }
  }
  bf8 hfrag[4];
  #pragma unroll
  for (int kk = 0; kk < 4; ++kk)
    hfrag[kk] = *(const bf8*)(So + (w * 16 + r0) * 136 + kk * 32 + g * 8);
  {
    uint4* S2 = (uint4*)(smem + 17408);
    const uint4* Pv2 = (const uint4*)Pp2;
    for (int t = tid; t < 2048; t += 256) S2[t] = Pv2[t];
  }
  __syncthreads();

  #pragma unroll
  for (int t = 0; t < 8; ++t) acc[t] = (f4){0.f, 0.f, 0.f, 0.f};
  const bf8* W2 = (const bf8*)(smem + 17408);
  #pragma unroll
  for (int kk = 0; kk < 4; ++kk) {
    #pragma unroll
    for (int t = 0; t < 8; ++t)
      acc[t] = __builtin_amdgcn_mfma_f32_16x16x32_bf16(hfrag[kk], W2[(t * 4 + kk) * 64 + lane], acc[t], 0, 0, 0);
  }
  #pragma unroll
  for (int i = 0; i < 4; ++i)
    #pragma unroll
    for (int t = 0; t < 8; ++t)
      So[(w * 16 + g * 4 + i) * 136 + t * 16 + r0] = f2bf(fmaxf(acc[t][i] + bb2[t], 0.f));
  __syncthreads();
  {
    uint4* Og = (uint4*)(Yb + (size_t)base * NF);
    for (int c = tid; c < 1024; c += 256) {
      int row = c >> 4, ch = c & 15;
      if (row < maxrows) Og[c] = *(const uint4*)(So + row * 136 + ch * 8);
    }
  }
}

// ---------------- dual GEMM + l2norm + relu -> fp32 out ----------------

__global__ __launch_bounds__(256) void k_dual_out(
    const unsigned short* __restrict__ A0, const unsigned short* __restrict__ P0,
    const unsigned short* __restrict__ A1, const unsigned short* __restrict__ P1,
    const float* __restrict__ bias, float* __restrict__ Cout, int M) {
  __shared__ __align__(16) char smem[65536];
  int tid = threadIdx.x, w = tid >> 6, lane = tid & 63;
  int r0 = lane & 15, g = lane >> 4;
  int base = blockIdx.x * 64;
  int arow = min(base + w * 16 + r0, M - 1);

  {
    uint4* S = (uint4*)smem;
    const uint4* Pv0 = (const uint4*)P0;
    const uint4* Pv1 = (const uint4*)P1;
    for (int t = tid; t < 2048; t += 256) S[t] = Pv0[t];
    for (int t = tid; t < 2048; t += 256) S[2048 + t] = Pv1[t];
  }
  __syncthreads();

  f4 acc[8];
  #pragma unroll
  for (int t = 0; t < 8; ++t) acc[t] = (f4){0.f, 0.f, 0.f, 0.f};
  #pragma unroll
  for (int mat = 0; mat < 2; ++mat) {
    const unsigned short* A = (mat == 0) ? A0 : A1;
    const bf8* Ar = (const bf8*)(A + (size_t)arow * NF);
    const bf8* Wl = (const bf8*)smem + (size_t)mat * 2048;
    #pragma unroll
    for (int kk = 0; kk < 4; ++kk) {
      bf8 a = Ar[kk * 4 + g];
      #pragma unroll
      for (int t = 0; t < 8; ++t)
        acc[t] = __builtin_amdgcn_mfma_f32_16x16x32_bf16(a, Wl[(t * 4 + kk) * 64 + lane], acc[t], 0, 0, 0);
    }
  }

  float bb[8];
  #pragma unroll
  for (int t = 0; t < 8; ++t) bb[t] = bias[t * 16 + r0];
  float val[8][4];
  #pragma unroll
  for (int t = 0; t < 8; ++t)
    #pragma unroll
    for (int i = 0; i < 4; ++i) val[t][i] = acc[t][i] + bb[t];
  float ss[4] = {0.f, 0.f, 0.f, 0.f};
  #pragma unroll
  for (int i = 0; i < 4; ++i)
    #pragma unroll
    for (int t = 0; t < 8; ++t) ss[i] += val[t][i] * val[t][i];
  #pragma unroll
  for (int d = 1; d < 16; d <<= 1)
    #pragma unroll
    for (int i = 0; i < 4; ++i) ss[i] += __shfl_xor(ss[i], d, 64);
  float inv[4];
  #pragma unroll
  for (int i = 0; i < 4; ++i) inv[i] = 1.f / fmaxf(sqrtf(ss[i]), 1e-12f);

  __syncthreads();                     // W dead; reuse smem for fp32 staging (32 KB)
  int maxrows = min(64, M - base);
  float* So = (float*)smem;
  #pragma unroll
  for (int i = 0; i < 4; ++i)
    #pragma unroll
    for (int t = 0; t < 8; ++t)
      So[(w * 16 + g * 4 + i) * NF + t * 16 + r0] = fmaxf(val[t][i] * inv[i], 0.f);
  __syncthreads();
  uint4* Og = (uint4*)(Cout + (size_t)base * NF);
  const uint4* Sv = (const uint4*)smem;
  int maxc = maxrows * 32;
  for (int c = tid; c < 2048; c += 256)
    if (c < maxc) Og[c] = Sv[c];
}

// ---------------- launch ----------------

extern "C" void kernel_launch(void* const* d_in, const int* in_sizes, int n_in,
                              void* d_out, int out_size, void* d_ws, size_t ws_size,
                              hipStream_t stream) {
  const float* x   = (const float*)d_in[0];
  const int*   src = (const int*)d_in[1];
  const int*   dst = (const int*)d_in[2];
  const float* Wp1 = (const float*)d_in[3];
  const float* bp1 = (const float*)d_in[4];
  const float* Ws1 = (const float*)d_in[5];
  const float* Wn1 = (const float*)d_in[6];
  const float* b1  = (const float*)d_in[7];
  const float* Wp2 = (const float*)d_in[8];
  const float* bp2 = (const float*)d_in[9];
  const float* Ws2 = (const float*)d_in[10];
  const float* Wn2 = (const float*)d_in[11];
  const float* b2  = (const float*)d_in[12];
  float* out = (float*)d_out;

  const int N = in_sizes[0] / NF;
  const int E = in_sizes[1];

  char* ws = (char*)d_ws;
  auto carve = [&](size_t bytes) { char* p = ws; ws += (bytes + 255) & ~(size_t)255; return p; };
  unsigned short* Xb    = (unsigned short*)carve((size_t)N * NF * 2);
  unsigned short* Yb    = (unsigned short*)carve((size_t)N * NF * 2);
  unsigned short* AGGb  = (unsigned short*)carve((size_t)N * NF * 2);
  unsigned short* Hb    = (unsigned short*)carve((size_t)N * NF * 2);
  unsigned short* Wpack = (unsigned short*)carve((size_t)6 * NF * NF * 2);
  int* off     = (int*)carve((size_t)(N + 1) * 4);
  int* meta    = (int*)carve(512 * 4);           // bcnt[256] + gcur[256], one memset
  unsigned* tmp = (unsigned*)carve((size_t)E * 4);
  unsigned short* esrc = (unsigned short*)carve((size_t)E * 2);

  int* bcnt = meta;
  int* gcur = meta + 256;

  unsigned short* Pp1 = Wpack + 0 * NF * NF;
  unsigned short* Ps1 = Wpack + 1 * NF * NF;
  unsigned short* Pn1 = Wpack + 2 * NF * NF;
  unsigned short* Pp2 = Wpack + 3 * NF * NF;
  unsigned short* Ps2 = Wpack + 4 * NF * NF;
  unsigned short* Pn2 = Wpack + 5 * NF * NF;

  const long long nelX = (long long)N * NF;
  const int gConv = (int)((nelX / 8 + 255) / 256);
  const int gTile = (E + TILE_B - 1) / TILE_B;
  const int NB    = (N + 255) >> 8;
  const int gRW   = (N + 15) / 16;               // 4 dsts per wave, 4 waves per block
  const int T     = (N + 63) / 64;               // pool row-tiles
  const int Thalf = T / 2;

  hipMemsetAsync(meta, 0, 512 * 4, stream);
  k_prep<<<gConv, 256, 0, stream>>>(x, Xb, nelX, dst, bcnt, E, gTile,
                                    Wp1, Ws1, Wn1, Wp2, Ws2, Wn2, Wpack);
  // binB || pool-1 tiles [0, Thalf)
  k_binB_pool<<<gTile + Thalf, 256, 0, stream>>>(src, dst, bcnt, gcur, tmp, E, gTile,
                                                 Xb, Pp1, bp1, Yb, N);
  // binC || pool-1 tiles [Thalf, T)
  k_binC_pool<<<NB + (T - Thalf), 256, 0, stream>>>(tmp, bcnt, off, esrc, N, E, NB,
                                                    Xb, Pp1, bp1, Yb, N, Thalf);

  k_gather_max<<<gRW, 256, 0, stream>>>(Yb, off, esrc, AGGb, N);
  // dual-1 + l2norm + pool-2 chain: writes Hb and Yb
  k_dual_pool<<<T, 256, 0, stream>>>(Xb, Ps1, AGGb, Pn1, b1, Pp2, bp2, Hb, Yb, N);

  k_gather_max<<<gRW, 256, 0, stream>>>(Yb, off, esrc, AGGb, N);
  k_dual_out<<<T, 256, 0, stream>>>(Hb, Ps2, AGGb, Pn2, b2, out, N);
}

// Round 11
// 268.085 us; speedup vs baseline: 1.0711x; 1.0711x over previous
//
#include <hip/hip_runtime.h>
#include <hip/hip_bf16.h>

#define NF 128
#define TILE_B 4096
#define CSR_CAP 15360

typedef __attribute__((ext_vector_type(8))) short bf8;
typedef __attribute__((ext_vector_type(4))) float f4;
typedef unsigned short u16x8 __attribute__((ext_vector_type(8)));

static __device__ __forceinline__ unsigned short f2bf(float f) {
  unsigned u = __builtin_bit_cast(unsigned, f);
  u = u + 0x7FFF + ((u >> 16) & 1);            // RNE
  return (unsigned short)(u >> 16);
}

static __device__ __forceinline__ uint4 pkmax4(uint4 a, uint4 b) {
  u16x8 x = __builtin_bit_cast(u16x8, a);
  u16x8 y = __builtin_bit_cast(u16x8, b);
  u16x8 m = __builtin_elementwise_max(x, y);   // v_pk_max_u16: valid for relu'd bf16 (>=0)
  return __builtin_bit_cast(uint4, m);
}

static __device__ __forceinline__ uint4 shflxor4(uint4 a, int m) {
  uint4 r;
  r.x = (unsigned)__shfl_xor((int)a.x, m, 64);
  r.y = (unsigned)__shfl_xor((int)a.y, m, 64);
  r.z = (unsigned)__shfl_xor((int)a.z, m, 64);
  r.w = (unsigned)__shfl_xor((int)a.w, m, 64);
  return r;
}

// ---------------- prep: fp32->bf16 convert (all blocks) + dst bucket hist + W pack ----------------

__global__ __launch_bounds__(256) void k_prep(
    const float* __restrict__ x, unsigned short* __restrict__ Xb, long long nelX,
    const int* __restrict__ dst, int* __restrict__ bcnt, int E, int gTile,
    const float* W0, const float* W1, const float* W2,
    const float* W3, const float* W4, const float* W5,
    unsigned short* __restrict__ Wpack) {
  __shared__ int h[256];
  int b = blockIdx.x, tid = threadIdx.x;

  long long i = ((long long)b * 256 + tid) * 8;
  if (i + 8 <= nelX) {
    float4 a = *(const float4*)(x + i);
    float4 c = *(const float4*)(x + i + 4);
    uint4 o;
    o.x = f2bf(a.x) | ((unsigned)f2bf(a.y) << 16);
    o.y = f2bf(a.z) | ((unsigned)f2bf(a.w) << 16);
    o.z = f2bf(c.x) | ((unsigned)f2bf(c.y) << 16);
    o.w = f2bf(c.z) | ((unsigned)f2bf(c.w) << 16);
    *(uint4*)(Xb + i) = o;
  }

  if (b < gTile) {                       // bucket histogram tile
    h[tid] = 0;
    __syncthreads();
    int t0 = b * TILE_B;
    int tend = min(E, t0 + TILE_B);
    for (int k = t0 + tid; k < tend; k += 256) atomicAdd(&h[dst[k] >> 8], 1);
    __syncthreads();
    if (h[tid] > 0) atomicAdd(&bcnt[tid], h[tid]);
  } else if (b < gTile + 48) {           // pack 6 matrices: 48*256 = 6*2048 units
    int gid = (b - gTile) * 256 + tid;
    int m = gid >> 11;
    int u = gid & 2047;
    const float* W = (m == 0) ? W0 : (m == 1) ? W1 : (m == 2) ? W2
                   : (m == 3) ? W3 : (m == 4) ? W4 : W5;
    int l = u & 63, c = u >> 6;
    int kk = c & 3, t = c >> 2;
    int kb = kk * 32 + ((l >> 4) << 3);
    int n = t * 16 + (l & 15);
    unsigned short* o = Wpack + (size_t)m * 2048 * 8 + (size_t)u * 8;
    #pragma unroll
    for (int j = 0; j < 8; ++j) o[j] = f2bf(W[(size_t)(kb + j) * NF + n]);
  }
}

// ---------------- pool GEMM body: Y = relu(A@W + b), 64 rows/block, W in LDS (32 KB) ----------

static __device__ __forceinline__ void pool_body(
    char* smem, int tile,
    const unsigned short* __restrict__ A, const unsigned short* __restrict__ P,
    const float* __restrict__ bias, unsigned short* __restrict__ Yout, int M) {
  int tid = threadIdx.x, w = tid >> 6, lane = tid & 63;
  int r0 = lane & 15, g = lane >> 4;
  {
    uint4* S = (uint4*)smem;
    const uint4* Pv = (const uint4*)P;
    for (int t = tid; t < 2048; t += 256) S[t] = Pv[t];
  }
  float bb[8];
  #pragma unroll
  for (int t = 0; t < 8; ++t) bb[t] = bias[t * 16 + r0];
  __syncthreads();

  int base = tile * 64;
  int arow = min(base + w * 16 + r0, M - 1);
  f4 acc[8];
  #pragma unroll
  for (int t = 0; t < 8; ++t) acc[t] = (f4){0.f, 0.f, 0.f, 0.f};
  const bf8* Ar = (const bf8*)(A + (size_t)arow * NF);
  const bf8* Wl = (const bf8*)smem;
  #pragma unroll
  for (int kk = 0; kk < 4; ++kk) {
    bf8 a = Ar[kk * 4 + g];
    #pragma unroll
    for (int t = 0; t < 8; ++t)
      acc[t] = __builtin_amdgcn_mfma_f32_16x16x32_bf16(a, Wl[(t * 4 + kk) * 64 + lane], acc[t], 0, 0, 0);
  }
  __syncthreads();
  unsigned short* So = (unsigned short*)smem;   // 64x128 bf16 = 16 KB
  #pragma unroll
  for (int i = 0; i < 4; ++i)
    #pragma unroll
    for (int t = 0; t < 8; ++t)
      So[(w * 16 + g * 4 + i) * NF + t * 16 + r0] = f2bf(fmaxf(acc[t][i] + bb[t], 0.f));
  __syncthreads();
  int maxc = min(64, M - base) * 16;
  uint4* Og = (uint4*)(Yout + (size_t)base * NF);
  const uint4* Sv = (const uint4*)smem;
  for (int c = tid; c < 1024; c += 256)
    if (c < maxc) Og[c] = Sv[c];
}

// ---------------- K3: binB (tile counting-sort by 256-dst bucket) || pool-1 part A ----------

__global__ __launch_bounds__(256) void k_binB_pool(
    const int* __restrict__ src, const int* __restrict__ dst,
    const int* __restrict__ bcnt, int* __restrict__ gcur,
    unsigned* __restrict__ tmp, int E, int gTile,
    const unsigned short* __restrict__ A, const unsigned short* __restrict__ P,
    const float* __restrict__ bias, unsigned short* __restrict__ Yout, int M) {
  __shared__ __align__(16) char smem[37888];   // binB: 5KB ctl + 16KB sorted; pool: 32KB
  int b = blockIdx.x;
  if (b >= gTile) { pool_body(smem, b - gTile, A, P, bias, Yout, M); return; }

  int tid = threadIdx.x;
  int* h  = (int*)smem;
  int* hs = h + 256;
  int* gb = hs + 256;
  int* lc = gb + 256;
  int* bo = lc + 256;
  unsigned* sorted = (unsigned*)(bo + 256);

  int t0 = b * TILE_B;
  int tcnt = min(E - t0, TILE_B);

  int bv = bcnt[tid];                    // scan bcnt -> bo (exclusive)
  hs[tid] = bv;
  __syncthreads();
  for (int d = 1; d < 256; d <<= 1) {
    int t = (tid >= d) ? hs[tid - d] : 0;
    __syncthreads();
    hs[tid] += t;
    __syncthreads();
  }
  bo[tid] = hs[tid] - bv;
  h[tid] = 0;
  __syncthreads();

  for (int i = tid; i < tcnt; i += 256) atomicAdd(&h[dst[t0 + i] >> 8], 1);
  __syncthreads();
  int v = h[tid];
  hs[tid] = v;
  __syncthreads();
  for (int d = 1; d < 256; d <<= 1) {
    int t = (tid >= d) ? hs[tid - d] : 0;
    __syncthreads();
    hs[tid] += t;
    __syncthreads();
  }
  lc[tid] = 0;
  gb[tid] = bo[tid] + ((v > 0) ? atomicAdd(&gcur[tid], v) : 0);
  __syncthreads();
  for (int i = tid; i < tcnt; i += 256) {
    int d = dst[t0 + i];
    unsigned s = (unsigned)src[t0 + i];
    int bk = d >> 8;
    int p = (hs[bk] - h[bk]) + atomicAdd(&lc[bk], 1);
    sorted[p] = ((unsigned)bk << 24) | (s << 8) | (unsigned)(d & 255);
  }
  __syncthreads();
  for (int i = tid; i < tcnt; i += 256) {
    unsigned ev = sorted[i];
    int bk = ev >> 24;
    tmp[gb[bk] + (i - (hs[bk] - h[bk]))] = ev & 0xFFFFFFu;
  }
}

// ---------------- K4: binC (per-bucket CSR in LDS, coalesced flush) || pool-1 part B ----------

__global__ __launch_bounds__(256) void k_binC_pool(
    const unsigned* __restrict__ tmp, const int* __restrict__ bcnt,
    int* __restrict__ off, unsigned short* __restrict__ esrc, int N, int E, int NB,
    const unsigned short* __restrict__ A, const unsigned short* __restrict__ P,
    const float* __restrict__ bias, unsigned short* __restrict__ Yout, int M, int tileOff) {
  __shared__ __align__(16) char smem[66560];   // binC: 5KB ctl + 60KB csr; pool: 32KB
  int b = blockIdx.x;
  if (b >= NB) { pool_body(smem, tileOff + b - NB, A, P, bias, Yout, M); return; }

  int tid = threadIdx.x;
  int* s256 = (int*)smem;
  int* bo   = s256 + 256;
  int* lh   = bo + 256;
  int* ls   = lh + 256;
  int* lcur = ls + 256;
  int* csr  = lcur + 256;
  int base = b << 8;

  int bv = bcnt[tid];                    // scan bcnt -> bo (exclusive)
  s256[tid] = bv;
  __syncthreads();
  for (int d = 1; d < 256; d <<= 1) {
    int t = (tid >= d) ? s256[tid - d] : 0;
    __syncthreads();
    s256[tid] += t;
    __syncthreads();
  }
  bo[tid] = s256[tid] - bv;
  lh[tid] = 0;
  __syncthreads();

  int beg = bo[b];
  int cnt = bcnt[b];
  int end = beg + cnt;

  for (int i = beg + tid; i < end; i += 256) atomicAdd(&lh[tmp[i] & 255], 1);
  __syncthreads();
  int v = lh[tid];
  ls[tid] = v;
  __syncthreads();
  for (int d = 1; d < 256; d <<= 1) {
    int t = (tid >= d) ? ls[tid - d] : 0;
    __syncthreads();
    ls[tid] += t;
    __syncthreads();
  }
  if (base + tid < N) off[base + tid] = beg + (ls[tid] - v);
  if (b == 0 && tid == 0) off[N] = E;
  lcur[tid] = 0;
  __syncthreads();

  if (cnt <= CSR_CAP) {
    for (int i = beg + tid; i < end; i += 256) {
      unsigned e = tmp[i];
      int dl = (int)(e & 255);
      int p = (ls[dl] - lh[dl]) + atomicAdd(&lcur[dl], 1);
      csr[p] = (int)(e >> 8);
    }
    __syncthreads();
    for (int i = tid; i < cnt; i += 256) esrc[beg + i] = (unsigned short)csr[i];
  } else {                                // overflow fallback (never for this data)
    for (int i = beg + tid; i < end; i += 256) {
      unsigned e = tmp[i];
      int dl = (int)(e & 255);
      int p = (ls[dl] - lh[dl]) + atomicAdd(&lcur[dl], 1);
      esrc[beg + p] = (unsigned short)(e >> 8);
    }
  }
}

// ---------------- gather-max: one wave per dst node, 4 edges per dwordx4 instr (R5-best) ------

__global__ __launch_bounds__(256) void k_gather_max(
    const unsigned short* __restrict__ Y, const int* __restrict__ off,
    const unsigned short* __restrict__ esrc, unsigned short* __restrict__ AGG, int N) {
  int w = (blockIdx.x * 256 + threadIdx.x) >> 6;
  int lane = threadIdx.x & 63;
  if (w >= N) return;
  int r0 = lane & 15, g = lane >> 4;
  int s = __builtin_amdgcn_readfirstlane(off[w]);
  int e = __builtin_amdgcn_readfirstlane(off[w + 1]);
  uint4 am[4];
  #pragma unroll
  for (int j = 0; j < 4; ++j) am[j] = (uint4){0u, 0u, 0u, 0u};   // relu >= 0 -> 0 == empty fill
  for (int b0 = s; b0 < e; b0 += 64) {
    int cnt = min(64, e - b0);
    int idxv = (int)esrc[b0 + min(lane, cnt - 1)];   // coalesced ushort block load
    for (int i = 0; i < cnt; i += 16) {
      #pragma unroll
      for (int j = 0; j < 4; ++j) {                  // 4 edges per dwordx4 instr
        int eo = min(i + j * 4 + g, cnt - 1);
        int u = __shfl(idxv, eo, 64);
        uint4 v = *((const uint4*)(Y + (size_t)u * NF) + r0);
        am[j] = pkmax4(am[j], v);
      }
    }
  }
  uint4 a01 = pkmax4(am[0], am[1]);
  uint4 a23 = pkmax4(am[2], am[3]);
  uint4 a = pkmax4(a01, a23);
  a = pkmax4(a, shflxor4(a, 16));
  a = pkmax4(a, shflxor4(a, 32));
  if (g == 0) *(uint4*)(AGG + (size_t)w * NF + r0 * 8) = a;
}

// ---------------- fused: H = l2norm_relu(X@Ws + AGG@Wn + b1); Y2 = relu(H@Wp2 + bp2) --------
// 512 thr = 8 waves; 128 rows/block. LDS: Ws+Wn 64KB; then H-stage (128x136 bf16, 34816B)
// at [0,34816) + Wp2 at [34816,67584). Writes Hb and Yb.

__global__ __launch_bounds__(512) void k_dual_pool(
    const unsigned short* __restrict__ Xb, const unsigned short* __restrict__ Ps,
    const unsigned short* __restrict__ AGG, const unsigned short* __restrict__ Pn,
    const float* __restrict__ b1,
    const unsigned short* __restrict__ Pp2, const float* __restrict__ bp2,
    unsigned short* __restrict__ Hb, unsigned short* __restrict__ Yb, int M) {
  __shared__ __align__(16) char smem[67584];
  int tid = threadIdx.x, w = tid >> 6, lane = tid & 63;
  int r0 = lane & 15, g = lane >> 4;
  int base = blockIdx.x * 128;
  int arow = min(base + w * 16 + r0, M - 1);
  int maxrows = min(128, M - base);

  {
    uint4* S = (uint4*)smem;
    const uint4* Pv0 = (const uint4*)Ps;
    const uint4* Pv1 = (const uint4*)Pn;
    for (int t = tid; t < 2048; t += 512) S[t] = Pv0[t];
    for (int t = tid; t < 2048; t += 512) S[2048 + t] = Pv1[t];
  }
  float bb[8], bb2[8];
  #pragma unroll
  for (int t = 0; t < 8; ++t) { bb[t] = b1[t * 16 + r0]; bb2[t] = bp2[t * 16 + r0]; }
  __syncthreads();

  f4 acc[8];
  #pragma unroll
  for (int t = 0; t < 8; ++t) acc[t] = (f4){0.f, 0.f, 0.f, 0.f};
  #pragma unroll
  for (int mat = 0; mat < 2; ++mat) {
    const unsigned short* A = (mat == 0) ? Xb : AGG;
    const bf8* Ar = (const bf8*)(A + (size_t)arow * NF);
    const bf8* Wl = (const bf8*)smem + (size_t)mat * 2048;
    #pragma unroll
    for (int kk = 0; kk < 4; ++kk) {
      bf8 a = Ar[kk * 4 + g];
      #pragma unroll
      for (int t = 0; t < 8; ++t)
        acc[t] = __builtin_amdgcn_mfma_f32_16x16x32_bf16(a, Wl[(t * 4 + kk) * 64 + lane], acc[t], 0, 0, 0);
    }
  }

  float val[8][4];
  #pragma unroll
  for (int t = 0; t < 8; ++t)
    #pragma unroll
    for (int i = 0; i < 4; ++i) val[t][i] = acc[t][i] + bb[t];
  float ss[4] = {0.f, 0.f, 0.f, 0.f};
  #pragma unroll
  for (int i = 0; i < 4; ++i)
    #pragma unroll
    for (int t = 0; t < 8; ++t) ss[i] += val[t][i] * val[t][i];
  #pragma unroll
  for (int d = 1; d < 16; d <<= 1)
    #pragma unroll
    for (int i = 0; i < 4; ++i) ss[i] += __shfl_xor(ss[i], d, 64);
  float inv[4];
  #pragma unroll
  for (int i = 0; i < 4; ++i) inv[i] = 1.f / fmaxf(sqrtf(ss[i]), 1e-12f);

  __syncthreads();                     // W dead
  unsigned short* So = (unsigned short*)smem;   // 128 rows x 136 (padded) bf16
  #pragma unroll
  for (int i = 0; i < 4; ++i)
    #pragma unroll
    for (int t = 0; t < 8; ++t)
      So[(w * 16 + g * 4 + i) * 136 + t * 16 + r0] = f2bf(fmaxf(val[t][i] * inv[i], 0.f));
  __syncthreads();

  // write Hb (coalesced, from padded stage) + load H A-frags + stage Wp2
  {
    uint4* Og = (uint4*)(Hb + (size_t)base * NF);
    for (int c = tid; c < 2048; c += 512) {
      int row = c >> 4, ch = c & 15;
      if (row < maxrows) Og[c] = *(const uint4*)(So + row * 136 + ch * 8);
    }
  }
  bf8 hfrag[4];
  #pragma unroll
  for (int kk = 0; kk < 4; ++kk)
    hfrag[kk] = *(const bf8*)(So + (w * 16 + r0) * 136 + kk * 32 + g * 8);
  {
    uint4* S2 = (uint4*)(smem + 34816);
    const uint4* Pv2 = (const uint4*)Pp2;
    for (int t = tid; t < 2048; t += 512) S2[t] = Pv2[t];
  }
  __syncthreads();

  #pragma unroll
  for (int t = 0; t < 8; ++t) acc[t] = (f4){0.f, 0.f, 0.f, 0.f};
  const bf8* W2 = (const bf8*)(smem + 34816);
  #pragma unroll
  for (int kk = 0; kk < 4; ++kk) {
    #pragma unroll
    for (int t = 0; t < 8; ++t)
      acc[t] = __builtin_amdgcn_mfma_f32_16x16x32_bf16(hfrag[kk], W2[(t * 4 + kk) * 64 + lane], acc[t], 0, 0, 0);
  }
  #pragma unroll
  for (int i = 0; i < 4; ++i)
    #pragma unroll
    for (int t = 0; t < 8; ++t)
      So[(w * 16 + g * 4 + i) * 136 + t * 16 + r0] = f2bf(fmaxf(acc[t][i] + bb2[t], 0.f));
  __syncthreads();
  {
    uint4* Og = (uint4*)(Yb + (size_t)base * NF);
    for (int c = tid; c < 2048; c += 512) {
      int row = c >> 4, ch = c & 15;
      if (row < maxrows) Og[c] = *(const uint4*)(So + row * 136 + ch * 8);
    }
  }
}

// ---------------- dual GEMM + l2norm + relu -> fp32 out: 512 thr, 128 rows/block --------------

__global__ __launch_bounds__(512) void k_dual_out(
    const unsigned short* __restrict__ A0, const unsigned short* __restrict__ P0,
    const unsigned short* __restrict__ A1, const unsigned short* __restrict__ P1,
    const float* __restrict__ bias, float* __restrict__ Cout, int M) {
  __shared__ __align__(16) char smem[65536];
  int tid = threadIdx.x, w = tid >> 6, lane = tid & 63;
  int r0 = lane & 15, g = lane >> 4;
  int base = blockIdx.x * 128;
  int arow = min(base + w * 16 + r0, M - 1);

  {
    uint4* S = (uint4*)smem;
    const uint4* Pv0 = (const uint4*)P0;
    const uint4* Pv1 = (const uint4*)P1;
    for (int t = tid; t < 2048; t += 512) S[t] = Pv0[t];
    for (int t = tid; t < 2048; t += 512) S[2048 + t] = Pv1[t];
  }
  __syncthreads();

  f4 acc[8];
  #pragma unroll
  for (int t = 0; t < 8; ++t) acc[t] = (f4){0.f, 0.f, 0.f, 0.f};
  #pragma unroll
  for (int mat = 0; mat < 2; ++mat) {
    const unsigned short* A = (mat == 0) ? A0 : A1;
    const bf8* Ar = (const bf8*)(A + (size_t)arow * NF);
    const bf8* Wl = (const bf8*)smem + (size_t)mat * 2048;
    #pragma unroll
    for (int kk = 0; kk < 4; ++kk) {
      bf8 a = Ar[kk * 4 + g];
      #pragma unroll
      for (int t = 0; t < 8; ++t)
        acc[t] = __builtin_amdgcn_mfma_f32_16x16x32_bf16(a, Wl[(t * 4 + kk) * 64 + lane], acc[t], 0, 0, 0);
    }
  }

  float bb[8];
  #pragma unroll
  for (int t = 0; t < 8; ++t) bb[t] = bias[t * 16 + r0];
  float val[8][4];
  #pragma unroll
  for (int t = 0; t < 8; ++t)
    #pragma unroll
    for (int i = 0; i < 4; ++i) val[t][i] = acc[t][i] + bb[t];
  float ss[4] = {0.f, 0.f, 0.f, 0.f};
  #pragma unroll
  for (int i = 0; i < 4; ++i)
    #pragma unroll
    for (int t = 0; t < 8; ++t) ss[i] += val[t][i] * val[t][i];
  #pragma unroll
  for (int d = 1; d < 16; d <<= 1)
    #pragma unroll
    for (int i = 0; i < 4; ++i) ss[i] += __shfl_xor(ss[i], d, 64);
  float inv[4];
  #pragma unroll
  for (int i = 0; i < 4; ++i) inv[i] = 1.f / fmaxf(sqrtf(ss[i]), 1e-12f);

  __syncthreads();                     // W dead; reuse smem for fp32 staging (64 KB, 128x128)
  int maxrows = min(128, M - base);
  float* So = (float*)smem;
  #pragma unroll
  for (int i = 0; i < 4; ++i)
    #pragma unroll
    for (int t = 0; t < 8; ++t)
      So[(w * 16 + g * 4 + i) * NF + t * 16 + r0] = fmaxf(val[t][i] * inv[i], 0.f);
  __syncthreads();
  uint4* Og = (uint4*)(Cout + (size_t)base * NF);
  const uint4* Sv = (const uint4*)smem;
  int maxc = maxrows * 32;
  for (int c = tid; c < 4096; c += 512)
    if (c < maxc) Og[c] = Sv[c];
}

// ---------------- launch ----------------

extern "C" void kernel_launch(void* const* d_in, const int* in_sizes, int n_in,
                              void* d_out, int out_size, void* d_ws, size_t ws_size,
                              hipStream_t stream) {
  const float* x   = (const float*)d_in[0];
  const int*   src = (const int*)d_in[1];
  const int*   dst = (const int*)d_in[2];
  const float* Wp1 = (const float*)d_in[3];
  const float* bp1 = (const float*)d_in[4];
  const float* Ws1 = (const float*)d_in[5];
  const float* Wn1 = (const float*)d_in[6];
  const float* b1  = (const float*)d_in[7];
  const float* Wp2 = (const float*)d_in[8];
  const float* bp2 = (const float*)d_in[9];
  const float* Ws2 = (const float*)d_in[10];
  const float* Wn2 = (const float*)d_in[11];
  const float* b2  = (const float*)d_in[12];
  float* out = (float*)d_out;

  const int N = in_sizes[0] / NF;
  const int E = in_sizes[1];

  char* ws = (char*)d_ws;
  auto carve = [&](size_t bytes) { char* p = ws; ws += (bytes + 255) & ~(size_t)255; return p; };
  unsigned short* Xb    = (unsigned short*)carve((size_t)N * NF * 2);
  unsigned short* Yb    = (unsigned short*)carve((size_t)N * NF * 2);
  unsigned short* AGGb  = (unsigned short*)carve((size_t)N * NF * 2);
  unsigned short* Hb    = (unsigned short*)carve((size_t)N * NF * 2);
  unsigned short* Wpack = (unsigned short*)carve((size_t)6 * NF * NF * 2);
  int* off     = (int*)carve((size_t)(N + 1) * 4);
  int* meta    = (int*)carve(512 * 4);           // bcnt[256] + gcur[256], one memset
  unsigned* tmp = (unsigned*)carve((size_t)E * 4);
  unsigned short* esrc = (unsigned short*)carve((size_t)E * 2);

  int* bcnt = meta;
  int* gcur = meta + 256;

  unsigned short* Pp1 = Wpack + 0 * NF * NF;
  unsigned short* Ps1 = Wpack + 1 * NF * NF;
  unsigned short* Pn1 = Wpack + 2 * NF * NF;
  unsigned short* Pp2 = Wpack + 3 * NF * NF;
  unsigned short* Ps2 = Wpack + 4 * NF * NF;
  unsigned short* Pn2 = Wpack + 5 * NF * NF;

  const long long nelX = (long long)N * NF;
  const int gConv = (int)((nelX / 8 + 255) / 256);
  const int gTile = (E + TILE_B - 1) / TILE_B;
  const int NB    = (N + 255) >> 8;
  const int gRW   = (N + 3) / 4;                 // wave per dst, 4 waves/block
  const int T     = (N + 63) / 64;               // pool row-tiles (64 rows)
  const int Thalf = T / 2;
  const int D     = (N + 127) / 128;             // dual tiles (128 rows)

  hipMemsetAsync(meta, 0, 512 * 4, stream);
  k_prep<<<gConv, 256, 0, stream>>>(x, Xb, nelX, dst, bcnt, E, gTile,
                                    Wp1, Ws1, Wn1, Wp2, Ws2, Wn2, Wpack);
  // binB || pool-1 tiles [0, Thalf)
  k_binB_pool<<<gTile + Thalf, 256, 0, stream>>>(src, dst, bcnt, gcur, tmp, E, gTile,
                                                 Xb, Pp1, bp1, Yb, N);
  // binC || pool-1 tiles [Thalf, T)
  k_binC_pool<<<NB + (T - Thalf), 256, 0, stream>>>(tmp, bcnt, off, esrc, N, E, NB,
                                                    Xb, Pp1, bp1, Yb, N, Thalf);

  k_gather_max<<<gRW, 256, 0, stream>>>(Yb, off, esrc, AGGb, N);
  // dual-1 + l2norm + pool-2 chain: writes Hb and Yb
  k_dual_pool<<<D, 512, 0, stream>>>(Xb, Ps1, AGGb, Pn1, b1, Pp2, bp2, Hb, Yb, N);

  k_gather_max<<<gRW, 256, 0, stream>>>(Yb, off, esrc, AGGb, N);
  k_dual_out<<<D, 512, 0, stream>>>(Hb, Ps2, AGGb, Pn2, b2, out, N);
}